// Round 3
// baseline (146.880 us; speedup 1.0000x reference)
//
#include <hip/hip_runtime.h>

#define N 4096
#define D 1024
#define BM 128
#define BN 128
#define BK 32
#define NSLOT 32   // N / BM partial-slots per column
#define NTRI 528   // 32*33/2 lower-triangle blocks

typedef __bf16 bf16x8 __attribute__((ext_vector_type(8)));
typedef float floatx4 __attribute__((ext_vector_type(4)));

__device__ __forceinline__ ushort f2bf(float f) {
    union { float f; uint32_t u; } c; c.f = f;
    uint32_t u = c.u;
    uint32_t r = u + 0x7FFFu + ((u >> 16) & 1u);
    return (ushort)(r >> 16);
}

// ---------------------------------------------------------------------------
// Kernel 1: fp32 -> bf16 + per-row squared norm. One wave per row, no LDS.
// ---------------------------------------------------------------------------
__global__ __launch_bounds__(256) void prep_kernel(const float* __restrict__ x,
                                                   ushort* __restrict__ xb,
                                                   float* __restrict__ sq) {
    int row = blockIdx.x * 4 + (threadIdx.x >> 6);
    int lane = threadIdx.x & 63;
    const float4* xr = (const float4*)(x + (size_t)row * D);
    ushort4* br = (ushort4*)(xb + (size_t)row * D);
    float s = 0.f;
    #pragma unroll
    for (int j = 0; j < 4; ++j) {
        float4 v = xr[j * 64 + lane];
        s += v.x * v.x + v.y * v.y + v.z * v.z + v.w * v.w;
        br[j * 64 + lane] = make_ushort4(f2bf(v.x), f2bf(v.y), f2bf(v.z), f2bf(v.w));
    }
    #pragma unroll
    for (int sh = 1; sh < 64; sh <<= 1) s += __shfl_xor(s, sh);
    if (lane == 0) sq[row] = s;
}

// ---------------------------------------------------------------------------
// Kernel 2: triangular fused X.X^T GEMM + dist + masked exp reductions.
// Only bi >= bj tiles run (dist symmetric). Off-diagonal blocks emit BOTH
// column partials (slot bi, tile bj) and row partials (slot bj, tile bi).
// LDS layout is k-major within 16-row groups so fragment ds_read_b128 is
// base + lane*16 (conflict-free, m134 pattern).
// ---------------------------------------------------------------------------
__global__ __launch_bounds__(256, 2) void gemm_fused(const ushort* __restrict__ xb,
                                                     const float* __restrict__ sq,
                                                     float* __restrict__ colPart) {
    __shared__ ushort smem[2 * BM * BK];   // 16 KB: A groups then B groups

    // triangular decode: blockIdx.x -> (bi, bj), bi >= bj
    int kblk = blockIdx.x;
    int bi = (int)((sqrtf(8.0f * kblk + 1.0f) - 1.0f) * 0.5f);
    if ((bi + 1) * (bi + 2) / 2 <= kblk) bi++;
    if (bi * (bi + 1) / 2 > kblk) bi--;
    int bj = kblk - bi * (bi + 1) / 2;

    const int i0 = bi * BM, j0 = bj * BN;
    const int tid = threadIdx.x;
    const int lane = tid & 63, wave = tid >> 6;
    const int wm = wave >> 1, wn = wave & 1;        // 2x2 waves over 128x128
    const int quad = lane >> 4, c16 = lane & 15;

    // staging source coords (constant per thread): chunk -> (half, group, kc, r)
    // LDS position = chunk*16B; within a 1KB group, position p = kc*16 + r.
    int s_half[4], s_row[4], s_kc[4];
    #pragma unroll
    for (int it = 0; it < 4; ++it) {
        int chunk = it * 256 + tid;          // 1024 chunks of 16B
        int half = chunk >> 9;               // 0 = A, 1 = B (wave-uniform)
        int c = chunk & 511;
        int g = c >> 6, p = c & 63;
        s_half[it] = half;
        s_kc[it] = p >> 4;
        s_row[it] = g * 16 + (p & 15);
    }

    floatx4 acc[4][4];
    #pragma unroll
    for (int a = 0; a < 4; ++a)
        #pragma unroll
        for (int b = 0; b < 4; ++b) acc[a][b] = (floatx4){0.f, 0.f, 0.f, 0.f};

    for (int kt = 0; kt < D; kt += BK) {
        #pragma unroll
        for (int it = 0; it < 4; ++it) {
            int grow = (s_half[it] ? j0 : i0) + s_row[it];
            const ushort* gp = xb + (size_t)grow * D + kt + s_kc[it] * 8;
            ushort* lp = smem + (it * 256 + tid) * 8;   // lane-contiguous 16B
            __builtin_amdgcn_global_load_lds(
                (const __attribute__((address_space(1))) void*)gp,
                (__attribute__((address_space(3))) void*)lp, 16, 0, 0);
        }
        __syncthreads();   // drains vmcnt -> LDS tiles ready

        // fragment reads: group (wm*4+t), byte addr = group*1024 + lane*16
        bf16x8 afrag[4], bfrag[4];
        #pragma unroll
        for (int t = 0; t < 4; ++t) {
            afrag[t] = *(const bf16x8*)(smem + (wm * 4 + t) * 512 + lane * 8);
            bfrag[t] = *(const bf16x8*)(smem + 4096 + (wn * 4 + t) * 512 + lane * 8);
        }
        #pragma unroll
        for (int tm = 0; tm < 4; ++tm)
            #pragma unroll
            for (int tn = 0; tn < 4; ++tn)
                acc[tm][tn] = __builtin_amdgcn_mfma_f32_16x16x32_bf16(
                    afrag[tm], bfrag[tn], acc[tm][tn], 0, 0, 0);
        __syncthreads();   // protect LDS before next stage overwrites
    }

    // ---- epilogue ----
    // C/D layout: col = c16, row = quad*4 + r   [measured m89/m91]
    float sqi[4][4];
    #pragma unroll
    for (int tm = 0; tm < 4; ++tm)
        #pragma unroll
        for (int r = 0; r < 4; ++r)
            sqi[tm][r] = sq[i0 + wm * 64 + tm * 16 + quad * 4 + r];
    float sqj[4];
    #pragma unroll
    for (int tn = 0; tn < 4; ++tn)
        sqj[tn] = sq[j0 + wn * 64 + tn * 16 + c16];

    float* colBuf = (float*)smem;          // [2][128][6] = 3072 floats
    float* rowBuf = colBuf + 1536;         // [2][128][6]
    const bool diag = (bi == bj);          // same-class pairs only here (8|128)

    if (!diag) {
        // pure negatives, both directions (row sums == transposed col sums)
        float rna[4][4], rnb[4][4], rnd[4][4];
        #pragma unroll
        for (int tm = 0; tm < 4; ++tm)
            #pragma unroll
            for (int r = 0; r < 4; ++r) { rna[tm][r] = 0.f; rnb[tm][r] = 0.f; rnd[tm][r] = 0.f; }

        #pragma unroll
        for (int tn = 0; tn < 4; ++tn) {
            float na = 0.f, nb = 0.f, nd = 0.f;
            #pragma unroll
            for (int tm = 0; tm < 4; ++tm)
                #pragma unroll
                for (int r = 0; r < 4; ++r) {
                    float dot = acc[tm][tn][r];
                    float dsq = sqi[tm][r] + sqj[tn] - 2.0f * dot;
                    float dist = sqrtf(fmaxf(dsq, 1e-12f));
                    float t = __expf(20.0f * (1.1f - dist));   // exp(BETA(1.1-d))
                    na = fmaf(t, t, na);                        // e^4 * exp(40(1-d))
                    nb += t;
                    nd += dist;
                    rna[tm][r] = fmaf(t, t, rna[tm][r]);
                    rnb[tm][r] += t;
                    rnd[tm][r] += dist;
                }
            #pragma unroll
            for (int s = 16; s < 64; s <<= 1) {
                na += __shfl_xor(na, s); nb += __shfl_xor(nb, s); nd += __shfl_xor(nd, s);
            }
            int cb = (wm * 128 + wn * 64 + tn * 16 + c16) * 6;
            colBuf[cb + 0] = 0.f; colBuf[cb + 1] = na;
            colBuf[cb + 2] = 0.f; colBuf[cb + 3] = nb;
            colBuf[cb + 4] = 0.f; colBuf[cb + 5] = nd;
        }
        // row direction: reduce across the 16 c16 lanes
        #pragma unroll
        for (int tm = 0; tm < 4; ++tm)
            #pragma unroll
            for (int r = 0; r < 4; ++r) {
                float a = rna[tm][r], b = rnb[tm][r], d = rnd[tm][r];
                #pragma unroll
                for (int s = 1; s < 16; s <<= 1) {
                    a += __shfl_xor(a, s); b += __shfl_xor(b, s); d += __shfl_xor(d, s);
                }
                if (c16 == 0) {
                    int rb = (wn * 128 + wm * 64 + tm * 16 + quad * 4 + r) * 6;
                    rowBuf[rb + 0] = 0.f; rowBuf[rb + 1] = a;
                    rowBuf[rb + 2] = 0.f; rowBuf[rb + 3] = b;
                    rowBuf[rb + 4] = 0.f; rowBuf[rb + 5] = d;
                }
            }
    } else {
        // diagonal tile: pos/neg masks live here; column sums only
        #pragma unroll
        for (int tn = 0; tn < 4; ++tn) {
            const int gj = j0 + wn * 64 + tn * 16 + c16;
            const int gjc = gj >> 3;
            float pa = 0.f, na = 0.f, pb = 0.f, nb = 0.f, pd = 0.f, nd = 0.f;
            #pragma unroll
            for (int tm = 0; tm < 4; ++tm)
                #pragma unroll
                for (int r = 0; r < 4; ++r) {
                    const int gi = i0 + wm * 64 + tm * 16 + quad * 4 + r;
                    float dot = acc[tm][tn][r];
                    float dsq = sqi[tm][r] + sqj[tn] - 2.0f * dot;
                    float dist = sqrtf(fmaxf(dsq, 1e-12f));
                    float t = __expf(20.0f * (1.1f - dist));
                    bool same = (gi >> 3) == gjc;
                    if (same) {
                        if (gi != gj) {
                            pa = fmaf(t, t, pa);
                            pb += __expf(20.0f * (dist - 0.8f));
                            pd += dist;
                        }
                    } else {
                        na = fmaf(t, t, na);
                        nb += t;
                        nd += dist;
                    }
                }
            #pragma unroll
            for (int s = 16; s < 64; s <<= 1) {
                pa += __shfl_xor(pa, s); na += __shfl_xor(na, s);
                pb += __shfl_xor(pb, s); nb += __shfl_xor(nb, s);
                pd += __shfl_xor(pd, s); nd += __shfl_xor(nd, s);
            }
            int cb = (wm * 128 + wn * 64 + tn * 16 + c16) * 6;
            colBuf[cb + 0] = pa; colBuf[cb + 1] = na;
            colBuf[cb + 2] = pb; colBuf[cb + 3] = nb;
            colBuf[cb + 4] = pd; colBuf[cb + 5] = nd;
        }
    }
    __syncthreads();

    // atomic-free partial stores (each slot written by exactly one block)
    float* dstC = colPart + ((size_t)bi * N + j0) * 6;
    #pragma unroll
    for (int it = 0; it < 3; ++it) {
        int idx = it * 256 + tid;               // 0..767
        dstC[idx] = colBuf[idx] + colBuf[768 + idx];
    }
    if (!diag) {
        float* dstR = colPart + ((size_t)bj * N + i0) * 6;
        #pragma unroll
        for (int it = 0; it < 3; ++it) {
            int idx = it * 256 + tid;
            dstR[idx] = rowBuf[idx] + rowBuf[768 + idx];
        }
    }
}

// ---------------------------------------------------------------------------
// Kernel 3: reduce the 32 per-block partial slots -> per-row loss pieces
// ---------------------------------------------------------------------------
__global__ __launch_bounds__(256) void reduce_rows(const float* __restrict__ colPart,
                                                   float* __restrict__ rowOut) {
    int j = blockIdx.x * 256 + threadIdx.x;     // 4096 threads total
    float pa = 0.f, na = 0.f, pb = 0.f, nb = 0.f, pd = 0.f, nd = 0.f;
    for (int s = 0; s < NSLOT; ++s) {
        const float* p = colPart + (size_t)s * N * 6 + (size_t)j * 6;
        pa += p[0]; na += p[1]; pb += p[2];
        nb += p[3]; pd += p[4]; nd += p[5];
    }
    // pa/na both carry the same e^4 factor vs exp(40(1-d)) -> cancels in a_lr
    float a_lr = 1.0f - pa / (pa + na);
    rowOut[j * 3 + 0] = a_lr * (logf(pb) + logf(nb));
    rowOut[j * 3 + 1] = pd;
    rowOut[j * 3 + 2] = nd;
}

// ---------------------------------------------------------------------------
// Kernel 4: global means
// ---------------------------------------------------------------------------
__global__ __launch_bounds__(256) void finalize_kernel(const float* __restrict__ rowOut,
                                                       float* __restrict__ out) {
    int tid = threadIdx.x;
    float L = 0.f, P = 0.f, G = 0.f;
    for (int i = tid; i < N; i += 256) {
        L += rowOut[i * 3 + 0];
        P += rowOut[i * 3 + 1];
        G += rowOut[i * 3 + 2];
    }
    #pragma unroll
    for (int s = 1; s < 64; s <<= 1) {
        L += __shfl_xor(L, s);
        P += __shfl_xor(P, s);
        G += __shfl_xor(G, s);
    }
    __shared__ float r0[4], r1[4], r2[4];
    int lane = tid & 63, w = tid >> 6;
    if (lane == 0) { r0[w] = L; r1[w] = P; r2[w] = G; }
    __syncthreads();
    if (tid == 0) {
        float Ls = r0[0] + r0[1] + r0[2] + r0[3];
        float Ps = r1[0] + r1[1] + r1[2] + r1[3];
        float Gs = r2[0] + r2[1] + r2[2] + r2[3];
        out[0] = Ls / (float)N;
        out[1] = 0.0f;                                   // accuracy never incremented
        out[2] = Ps / ((float)N * 7.0f);                 // pos pairs per row = 7
        out[3] = Gs / ((float)N * (float)(N - 8));       // neg pairs per row = 4088
    }
}

// ---------------------------------------------------------------------------
extern "C" void kernel_launch(void* const* d_in, const int* in_sizes, int n_in,
                              void* d_out, int out_size, void* d_ws, size_t ws_size,
                              hipStream_t stream) {
    const float* x = (const float*)d_in[0];
    float* out = (float*)d_out;
    char* ws = (char*)d_ws;

    ushort* xb      = (ushort*)ws;                                   // 8 MB bf16 matrix
    float*  sq      = (float*)(ws + (size_t)N * D * 2);              // 16 KB row norms
    float*  colPart = (float*)(ws + (size_t)N * D * 2 + N * 4);      // 3 MB partials
    float*  rowOut  = (float*)(ws + (size_t)N * D * 2 + N * 4
                               + (size_t)NSLOT * N * 6 * 4);         // 48 KB

    prep_kernel<<<N / 4, 256, 0, stream>>>(x, xb, sq);

    gemm_fused<<<NTRI, 256, 0, stream>>>(xb, sq, colPart);

    reduce_rows<<<N / 256, 256, 0, stream>>>(colPart, rowOut);
    finalize_kernel<<<1, 256, 0, stream>>>(rowOut, out);
}